// Round 12
// baseline (6367.978 us; speedup 1.0000x reference)
//
#include <hip/hip_runtime.h>
#include <stdint.h>

#define TSTEPS 512
#define BATCH  32
#define HID    512
#define G4     2048
#define OUTW   1024
#define MTOT   (TSTEPS * BATCH)   // 16384, m = t*32 + b

#define NBLK   16                 // scan blocks per direction
#define KROW   528                // HST row stride (bytes): 64 k8-rows x [32 b x 16B]
#define HSZ    (64 * KROW)        // 33792 B (single hi plane)
#define ZLBYTES (128 * 33 * 4)    // 16896 B

typedef __attribute__((ext_vector_type(8))) short bf16x8;
typedef __attribute__((ext_vector_type(4))) float f32x4;

__device__ __forceinline__ float sigf(float x) { return 1.0f / (1.0f + __expf(-x)); }
__device__ __forceinline__ float tanhf_fast(float x) { return 2.0f / (1.0f + __expf(-2.0f * x)) - 1.0f; }

__device__ __forceinline__ unsigned short f2bf(float f) {
    unsigned int u = __float_as_uint(f);
    u += 0x7fffu + ((u >> 16) & 1u);
    return (unsigned short)(u >> 16);
}
__device__ __forceinline__ float bf2f(unsigned short u) {
    return __uint_as_float((unsigned int)u << 16);
}
__device__ __forceinline__ void addxw(f32x4& a, uint2 u) {
    a.x += bf2f((unsigned short)(u.x & 0xffff));
    a.y += bf2f((unsigned short)(u.x >> 16));
    a.z += bf2f((unsigned short)(u.y & 0xffff));
    a.w += bf2f((unsigned short)(u.y >> 16));
}

// ---------------------------------------------------------------------------
// MFMA input-projection GEMM (proven R7), transposed bf16 XWt[n][m].
// ---------------------------------------------------------------------------
__global__ __launch_bounds__(256) void gemm_xw_mfma(
    const float* __restrict__ X, int K,
    const float* __restrict__ W,
    const float* __restrict__ bias,
    unsigned short* __restrict__ XWt)
{
    extern __shared__ char gsm[];
    char* Abuf = gsm;
    char* Bbuf = gsm + 18432;

    const int tid = threadIdx.x;
    const int n0 = blockIdx.x * 128;
    const int m0 = blockIdx.y * 128;
    const int w  = tid >> 6;
    const int l  = tid & 63;
    const int lc16 = l & 15;
    const int lq4  = l >> 4;
    const int wr = w >> 1, wc = w & 1;

    const int ar  = tid >> 1;
    const int akh = tid & 1;
    const int mg  = m0 + ar;
    const float* aptr = X + (size_t)(mg & 31) * ((size_t)TSTEPS * K)
                          + (size_t)(mg >> 5) * K + akh * 16;
    const int bnp = tid & 63;
    const int bkg = tid >> 6;
    const float* bptr = W + n0 + bnp * 2;

    f32x4 acc[4][4];
    #pragma unroll
    for (int i = 0; i < 4; ++i)
        #pragma unroll
        for (int j = 0; j < 4; ++j) acc[i][j] = (f32x4){0.f, 0.f, 0.f, 0.f};

    const int KT = K >> 5;
    float4 a0, a1, a2, a3;
    float2 bw[8];

#define GLOADS(KT0) do { \
    const float* ap = aptr + (KT0) * 32; \
    a0 = *(const float4*)(ap);      a1 = *(const float4*)(ap + 4); \
    a2 = *(const float4*)(ap + 8);  a3 = *(const float4*)(ap + 12); \
    _Pragma("unroll") \
    for (int i = 0; i < 8; ++i) \
        bw[i] = *(const float2*)(bptr + (size_t)((KT0) * 32 + bkg * 8 + i) * G4); \
} while (0)

    GLOADS(0);

    for (int kt = 0; kt < KT; ++kt) {
        __syncthreads();
        {
            float av[16] = {a0.x,a0.y,a0.z,a0.w, a1.x,a1.y,a1.z,a1.w,
                            a2.x,a2.y,a2.z,a2.w, a3.x,a3.y,a3.z,a3.w};
            bf16x8 h0, h1, l0, l1;
            #pragma unroll
            for (int i = 0; i < 8; ++i) {
                unsigned short hh = f2bf(av[i]);
                h0[i] = (short)hh; l0[i] = (short)f2bf(av[i] - bf2f(hh));
                unsigned short hh2 = f2bf(av[i + 8]);
                h1[i] = (short)hh2; l1[i] = (short)f2bf(av[i + 8] - bf2f(hh2));
            }
            char* ab = Abuf + ar * 144 + akh * 32;
            *(bf16x8*)(ab)      = h0;
            *(bf16x8*)(ab + 16) = h1;
            *(bf16x8*)(ab + 64) = l0;
            *(bf16x8*)(ab + 80) = l1;
        }
        {
            bf16x8 bh[2], bl[2];
            #pragma unroll
            for (int c = 0; c < 2; ++c) {
                #pragma unroll
                for (int i = 0; i < 8; ++i) {
                    float v = c ? bw[i].y : bw[i].x;
                    unsigned short hh = f2bf(v);
                    bh[c][i] = (short)hh;
                    bl[c][i] = (short)f2bf(v - bf2f(hh));
                }
                char* bb = Bbuf + (bnp * 2 + c) * 144 + bkg * 16;
                *(bf16x8*)(bb)      = bh[c];
                *(bf16x8*)(bb + 64) = bl[c];
            }
        }
        __syncthreads();
        if (kt + 1 < KT) GLOADS(kt + 1);

        bf16x8 ah[4], al[4], bh[4], bl[4];
        #pragma unroll
        for (int rt = 0; rt < 4; ++rt) {
            const char* ab = Abuf + (wr * 64 + rt * 16 + lc16) * 144 + lq4 * 16;
            ah[rt] = *(const bf16x8*)(ab);
            al[rt] = *(const bf16x8*)(ab + 64);
        }
        #pragma unroll
        for (int ct = 0; ct < 4; ++ct) {
            const char* bb = Bbuf + (wc * 64 + ct * 16 + lc16) * 144 + lq4 * 16;
            bh[ct] = *(const bf16x8*)(bb);
            bl[ct] = *(const bf16x8*)(bb + 64);
        }
        #pragma unroll
        for (int rt = 0; rt < 4; ++rt)
            #pragma unroll
            for (int ct = 0; ct < 4; ++ct) {
                acc[rt][ct] = __builtin_amdgcn_mfma_f32_16x16x32_bf16(ah[rt], bh[ct], acc[rt][ct], 0, 0, 0);
                acc[rt][ct] = __builtin_amdgcn_mfma_f32_16x16x32_bf16(al[rt], bh[ct], acc[rt][ct], 0, 0, 0);
                acc[rt][ct] = __builtin_amdgcn_mfma_f32_16x16x32_bf16(ah[rt], bl[ct], acc[rt][ct], 0, 0, 0);
            }
    }
#undef GLOADS

    #pragma unroll
    for (int ct = 0; ct < 4; ++ct) {
        const int n = n0 + wc * 64 + ct * 16 + lc16;
        const float bn = bias[n];
        #pragma unroll
        for (int rt = 0; rt < 4; ++rt) {
            const int m = m0 + wr * 64 + rt * 16 + lq4 * 4;
            f32x4 v = acc[rt][ct];
            uint2 pk;
            pk.x = (unsigned)f2bf(v.x + bn) | ((unsigned)f2bf(v.y + bn) << 16);
            pk.y = (unsigned)f2bf(v.z + bn) | ((unsigned)f2bf(v.w + bn) << 16);
            *(uint2*)(XWt + (size_t)n * MTOT + m) = pk;
        }
    }
}

// ---------------------------------------------------------------------------
// MFMA recurrent scan (R10 structure; per-wave drain + LDS-counter flag;
// 2 barriers/step; out-store hidden under publish drain; xw after poll).
// 32 blocks x 256 thr (4 waves), dir = blk&1, P = blk>>1.
// ---------------------------------------------------------------------------
__global__ __launch_bounds__(256, 1) void lstm_scan10(
    const unsigned short* __restrict__ xw_f,   // [G4][MTOT] bf16
    const unsigned short* __restrict__ xw_b,
    const float* __restrict__ Wh_f,            // [512][2048] f32
    const float* __restrict__ Wh_b,
    float* __restrict__ out,                   // [B][T][1024] f32
    unsigned short* __restrict__ hbuf,         // [dir][par][P][b][32c] bf16 hi
    int* __restrict__ flags,                   // [dir][TSTEPS][16]
    int lval)                                  // layer+1
{
    extern __shared__ char smem[];
    float* ZL = (float*)(smem + HSZ);                        // [128 zc][33]
    unsigned int* cnt = (unsigned int*)(smem + HSZ + ZLBYTES); // monotonic

    const int tid  = threadIdx.x;
    const int l    = tid & 63;
    const int w    = tid >> 6;
    const int dir  = blockIdx.x & 1;
    const int P    = blockIdx.x >> 1;
    const int p_eff = P * 4 + w;
    const int lc16 = l & 15;
    const int lq4  = l >> 4;

    const unsigned short* __restrict__ xw = dir ? xw_b : xw_f;
    const float* __restrict__ Wh = dir ? Wh_b : Wh_f;
    char* hb  = (char*)hbuf + (size_t)dir * 65536;   // 32KB per parity, hi only
    int*  flg = flags + dir * TSTEPS * 16;

    if (tid == 0) *cnt = 0;    // ordered before first use by bar2 of s=0

    // ---- one-time: Wh fragments -> registers (hi/lo bf16) ----
    bf16x8 wfh[16][2], wfl[16][2];
    #pragma unroll
    for (int ki = 0; ki < 16; ++ki) {
        #pragma unroll
        for (int ct = 0; ct < 2; ++ct) {
            const int zc  = ct * 16 + lc16;
            const int col = p_eff * 8 + (zc & 7) + 512 * (zc >> 3);
            const float* src = Wh + (size_t)(ki * 32 + lq4 * 8) * G4 + col;
            bf16x8 vh, vl;
            #pragma unroll
            for (int r = 0; r < 8; ++r) {
                float v = src[(size_t)r * G4];
                unsigned short h16 = f2bf(v);
                vh[r] = (short)h16;
                vl[r] = (short)f2bf(v - bf2f(h16));
            }
            wfh[ki][ct] = vh;
            wfl[ki][ct] = vl;
        }
    }

    const int gc0 = p_eff * 8 + (lc16 & 7) + 512 * (lc16 >> 3);
    const unsigned short* xc0 = xw + (size_t)gc0 * MTOT;
    const unsigned short* xc1 = xw + (size_t)(gc0 + 1024) * MTOT;

    const int gb = tid & 31;                   // gate-thread batch
    const int jg = tid >> 5;                   // col group (cols jg*4..+3)
    float* outg = out + (size_t)gb * TSTEPS * OUTW + dir * HID + P * 32 + jg * 4;
    float cq[4] = {0.f, 0.f, 0.f, 0.f};

    for (int s = 0; s < TSTEPS; ++s) {
        const int t = dir ? (TSTEPS - 1 - s) : s;

        if (s > 0) {
            // ---- poll the 16 per-producer flag slots (clean vmcnt: no
            //      other VM ops outstanding for this wave at this point) ----
            const int* fp = &flg[(s - 1) * 16 + (l & 15)];
            int fv;
            do {
                asm volatile("global_load_dword %0, %1, off sc0 sc1\n\t"
                             "s_waitcnt vmcnt(0)"
                             : "=v"(fv) : "v"(fp) : "memory");
            } while (__any(fv != lval));
        }

        // xw loads AFTER the poll: latency hides under stage RT + MFMA
        const int xoff = t * 32 + lq4 * 4;
        uint2 u00 = *(const uint2*)(xc0 + xoff);
        uint2 u10 = *(const uint2*)(xc0 + xoff + 16);
        uint2 u01 = *(const uint2*)(xc1 + xoff);
        uint2 u11 = *(const uint2*)(xc1 + xoff + 16);

        f32x4 acc00 = {0,0,0,0}, acc01 = {0,0,0,0}, acc10 = {0,0,0,0}, acc11 = {0,0,0,0};

        if (s > 0) {
            // ---- issue 8 staging loads (32KB hi plane) ----
            // poll(s-1) already guarantees every sibling wave finished its
            // HST reads (publish(s-1) follows MFMA(s-1)) -> no pre-barrier.
            const char* hsrc = hb + ((s - 1) & 1) * 32768;
            float4 rg[8];
            #pragma unroll
            for (int c = 0; c < 8; ++c) {
                const char* sp = hsrc + c * 4096 + tid * 16;
                asm volatile("global_load_dwordx4 %0, %1, off sc0 sc1"
                             : "=v"(rg[c]) : "v"(sp) : "memory");
            }
#define STG_WRITE(C0) do { \
            _Pragma("unroll") \
            for (int c = (C0); c < (C0) + 4; ++c) { \
                const int ip  = c * 4096 + tid * 16; \
                const int Pq  = ip >> 11; \
                const int b   = (ip >> 6) & 31; \
                const int jb  = ip & 63; \
                *(float4*)(smem + (Pq * 4 + (jb >> 4)) * KROW + b * 16) = rg[c]; \
            } } while (0)
            asm volatile("s_waitcnt vmcnt(4)" ::: "memory");
            __builtin_amdgcn_sched_barrier(0);
            STG_WRITE(0);
            asm volatile("s_waitcnt vmcnt(0)" ::: "memory");
            __builtin_amdgcn_sched_barrier(0);
            STG_WRITE(4);
#undef STG_WRITE
            __syncthreads();                               // [bar 1]

            // ---- MFMA: A (h hi) from LDS, B (Wh hi+lo) from registers ----
            #pragma unroll
            for (int ki = 0; ki < 16; ++ki) {
                const char* ra = smem + (ki * 4 + lq4) * KROW + lc16 * 16;
                bf16x8 ah0 = *(const bf16x8*)ra;
                bf16x8 ah1 = *(const bf16x8*)(ra + 256);
                acc00 = __builtin_amdgcn_mfma_f32_16x16x32_bf16(ah0, wfh[ki][0], acc00, 0, 0, 0);
                acc10 = __builtin_amdgcn_mfma_f32_16x16x32_bf16(ah1, wfh[ki][0], acc10, 0, 0, 0);
                acc01 = __builtin_amdgcn_mfma_f32_16x16x32_bf16(ah0, wfh[ki][1], acc01, 0, 0, 0);
                acc11 = __builtin_amdgcn_mfma_f32_16x16x32_bf16(ah1, wfh[ki][1], acc11, 0, 0, 0);
                acc00 = __builtin_amdgcn_mfma_f32_16x16x32_bf16(ah0, wfl[ki][0], acc00, 0, 0, 0);
                acc10 = __builtin_amdgcn_mfma_f32_16x16x32_bf16(ah1, wfl[ki][0], acc10, 0, 0, 0);
                acc01 = __builtin_amdgcn_mfma_f32_16x16x32_bf16(ah0, wfl[ki][1], acc01, 0, 0, 0);
                acc11 = __builtin_amdgcn_mfma_f32_16x16x32_bf16(ah1, wfl[ki][1], acc11, 0, 0, 0);
            }
        }

        // ---- add xw ----
        addxw(acc00, u00); addxw(acc10, u10);
        addxw(acc01, u01); addxw(acc11, u11);

        // ---- z -> ZL[zc][b], stride 33 ----
        {
            const int cb = w * 32 + lc16;
            const int r0 = lq4 * 4;
            #pragma unroll
            for (int i = 0; i < 4; ++i) {
                ZL[cb * 33 + r0 + i]             = acc00[i];
                ZL[cb * 33 + 16 + r0 + i]        = acc10[i];
                ZL[(cb + 16) * 33 + r0 + i]      = acc01[i];
                ZL[(cb + 16) * 33 + 16 + r0 + i] = acc11[i];
            }
        }
        __syncthreads();                                   // [bar 2]

        // ---- gates: thread (b=gb, cols jg*4..+3) ----
        float hv[4];
        #pragma unroll
        for (int q = 0; q < 4; ++q) {
            const int j  = jg * 4 + q;
            const int wv = j >> 3;
            const int jj = j & 7;
            const int zb = wv * 32;
            float zi = ZL[(zb + jj) * 33 + gb];
            float zf = ZL[(zb + 8 + jj) * 33 + gb];
            float zg = ZL[(zb + 16 + jj) * 33 + gb];
            float zo = ZL[(zb + 24 + jj) * 33 + gb];
            float ig = sigf(zi);
            float fg = sigf(zf);
            float gg = tanhf_fast(zg);
            float og = sigf(zo);
            cq[q] = fmaf(fg, cq[q], ig * gg);
            hv[q] = og * tanhf_fast(cq[q]);
        }

        // out store FIRST: its L2 latency drains under the MALL publish
        {
            float4 ov; ov.x = hv[0]; ov.y = hv[1]; ov.z = hv[2]; ov.w = hv[3];
            *(float4*)&outg[(size_t)t * OUTW] = ov;
        }
        // ---- publish bf16-hi to MALL ----
        {
            unsigned short h0 = f2bf(hv[0]), h1 = f2bf(hv[1]);
            unsigned short h2 = f2bf(hv[2]), h3 = f2bf(hv[3]);
            uint2 hi_pk;
            hi_pk.x = (unsigned)h0 | ((unsigned)h1 << 16);
            hi_pk.y = (unsigned)h2 | ((unsigned)h3 << 16);
            char* wp = hb + (s & 1) * 32768 + P * 2048 + gb * 64 + jg * 8;
            asm volatile("global_store_dwordx2 %0, %1, off sc0 sc1"
                         :: "v"(wp), "v"(hi_pk) : "memory");
        }
        asm volatile("s_waitcnt vmcnt(0)" ::: "memory");   // per-wave drain
        if (l == 0) {
            unsigned int old = atomicAdd(cnt, 1u);
            if (old == (unsigned int)(4 * s + 3)) {        // last wave of block
                int* fp = &flg[s * 16 + P];
                asm volatile("global_store_dword %0, %1, off sc0 sc1"
                             :: "v"(fp), "v"(lval) : "memory");
            }
        }
    }
}

extern "C" void kernel_launch(void* const* d_in, const int* in_sizes, int n_in,
                              void* d_out, int out_size, void* d_ws, size_t ws_size,
                              hipStream_t stream)
{
    const float* x     = (const float*)d_in[0];
    const float* Wi_f0 = (const float*)d_in[1];
    const float* Wh_f0 = (const float*)d_in[2];
    const float* b_f0  = (const float*)d_in[3];
    const float* Wi_b0 = (const float*)d_in[4];
    const float* Wh_b0 = (const float*)d_in[5];
    const float* b_b0  = (const float*)d_in[6];
    const float* Wi_f1 = (const float*)d_in[7];
    const float* Wh_f1 = (const float*)d_in[8];
    const float* b_f1  = (const float*)d_in[9];
    const float* Wi_b1 = (const float*)d_in[10];
    const float* Wh_b1 = (const float*)d_in[11];
    const float* b_b1  = (const float*)d_in[12];
    float* out = (float*)d_out;

    const size_t xw_elems = (size_t)MTOT * G4;                 // 33,554,432
    unsigned short* xwf = (unsigned short*)d_ws;
    unsigned short* xwb = xwf + xw_elems;
    char* tail = (char*)d_ws + 2 * xw_elems * sizeof(unsigned short);  // 128 MiB
    unsigned short* hbuf = (unsigned short*)tail;              // [dir][2 par][32KB]
    int* flags = (int*)(tail + 262144);                        // [dir][512][16]

    (void)hipMemsetAsync(flags, 0, 2 * TSTEPS * 16 * sizeof(int), stream);

    dim3 ggrid(G4 / 128, MTOT / 128);                          // (16, 128)
    dim3 gblock(256);
    const size_t gsmem = 36864;
    dim3 sgrid(2 * NBLK);                                      // 32 blocks
    dim3 sblock(256);
    const size_t ssmem = HSZ + ZLBYTES + 16;                   // 50,704 B

    gemm_xw_mfma<<<ggrid, gblock, gsmem, stream>>>(x, 256, Wi_f0, b_f0, xwf);
    gemm_xw_mfma<<<ggrid, gblock, gsmem, stream>>>(x, 256, Wi_b0, b_b0, xwb);
    lstm_scan10<<<sgrid, sblock, ssmem, stream>>>(xwf, xwb, Wh_f0, Wh_b0, out,
                                                  hbuf, flags, 1);
    gemm_xw_mfma<<<ggrid, gblock, gsmem, stream>>>(out, 1024, Wi_f1, b_f1, xwf);
    gemm_xw_mfma<<<ggrid, gblock, gsmem, stream>>>(out, 1024, Wi_b1, b_b1, xwb);
    lstm_scan10<<<sgrid, sblock, ssmem, stream>>>(xwf, xwb, Wh_f1, Wh_b1, out,
                                                  hbuf, flags, 2);
}

// Round 13
// 5323.680 us; speedup vs baseline: 1.1962x; 1.1962x over previous
//
#include <hip/hip_runtime.h>
#include <stdint.h>

#define TSTEPS 512
#define BATCH  32
#define HID    512
#define G4     2048
#define OUTW   1024
#define MTOT   (TSTEPS * BATCH)   // 16384, m = t*32 + b

#define NBLK   16                 // scan blocks per direction
#define KROW   528                // HST row stride (bytes): 64 k8-rows x [32 b x 16B]
#define HSZ    (64 * KROW)        // 33792 B (single hi plane)
#define ZLBYTES (128 * 33 * 4)    // 16896 B

typedef __attribute__((ext_vector_type(8))) short bf16x8;
typedef __attribute__((ext_vector_type(4))) float f32x4;

__device__ __forceinline__ float sigf(float x) { return 1.0f / (1.0f + __expf(-x)); }
__device__ __forceinline__ float tanhf_fast(float x) { return 2.0f / (1.0f + __expf(-2.0f * x)) - 1.0f; }

__device__ __forceinline__ unsigned short f2bf(float f) {
    unsigned int u = __float_as_uint(f);
    u += 0x7fffu + ((u >> 16) & 1u);
    return (unsigned short)(u >> 16);
}
__device__ __forceinline__ float bf2f(unsigned short u) {
    return __uint_as_float((unsigned int)u << 16);
}
__device__ __forceinline__ void addxw(f32x4& a, uint2 u) {
    a.x += bf2f((unsigned short)(u.x & 0xffff));
    a.y += bf2f((unsigned short)(u.x >> 16));
    a.z += bf2f((unsigned short)(u.y & 0xffff));
    a.w += bf2f((unsigned short)(u.y >> 16));
}

// ---------------------------------------------------------------------------
// MFMA input-projection GEMM (proven R7), transposed bf16 XWt[n][m].
// ---------------------------------------------------------------------------
__global__ __launch_bounds__(256) void gemm_xw_mfma(
    const float* __restrict__ X, int K,
    const float* __restrict__ W,
    const float* __restrict__ bias,
    unsigned short* __restrict__ XWt)
{
    extern __shared__ char gsm[];
    char* Abuf = gsm;
    char* Bbuf = gsm + 18432;

    const int tid = threadIdx.x;
    const int n0 = blockIdx.x * 128;
    const int m0 = blockIdx.y * 128;
    const int w  = tid >> 6;
    const int l  = tid & 63;
    const int lc16 = l & 15;
    const int lq4  = l >> 4;
    const int wr = w >> 1, wc = w & 1;

    const int ar  = tid >> 1;
    const int akh = tid & 1;
    const int mg  = m0 + ar;
    const float* aptr = X + (size_t)(mg & 31) * ((size_t)TSTEPS * K)
                          + (size_t)(mg >> 5) * K + akh * 16;
    const int bnp = tid & 63;
    const int bkg = tid >> 6;
    const float* bptr = W + n0 + bnp * 2;

    f32x4 acc[4][4];
    #pragma unroll
    for (int i = 0; i < 4; ++i)
        #pragma unroll
        for (int j = 0; j < 4; ++j) acc[i][j] = (f32x4){0.f, 0.f, 0.f, 0.f};

    const int KT = K >> 5;
    float4 a0, a1, a2, a3;
    float2 bw[8];

#define GLOADS(KT0) do { \
    const float* ap = aptr + (KT0) * 32; \
    a0 = *(const float4*)(ap);      a1 = *(const float4*)(ap + 4); \
    a2 = *(const float4*)(ap + 8);  a3 = *(const float4*)(ap + 12); \
    _Pragma("unroll") \
    for (int i = 0; i < 8; ++i) \
        bw[i] = *(const float2*)(bptr + (size_t)((KT0) * 32 + bkg * 8 + i) * G4); \
} while (0)

    GLOADS(0);

    for (int kt = 0; kt < KT; ++kt) {
        __syncthreads();
        {
            float av[16] = {a0.x,a0.y,a0.z,a0.w, a1.x,a1.y,a1.z,a1.w,
                            a2.x,a2.y,a2.z,a2.w, a3.x,a3.y,a3.z,a3.w};
            bf16x8 h0, h1, l0, l1;
            #pragma unroll
            for (int i = 0; i < 8; ++i) {
                unsigned short hh = f2bf(av[i]);
                h0[i] = (short)hh; l0[i] = (short)f2bf(av[i] - bf2f(hh));
                unsigned short hh2 = f2bf(av[i + 8]);
                h1[i] = (short)hh2; l1[i] = (short)f2bf(av[i + 8] - bf2f(hh2));
            }
            char* ab = Abuf + ar * 144 + akh * 32;
            *(bf16x8*)(ab)      = h0;
            *(bf16x8*)(ab + 16) = h1;
            *(bf16x8*)(ab + 64) = l0;
            *(bf16x8*)(ab + 80) = l1;
        }
        {
            bf16x8 bh[2], bl[2];
            #pragma unroll
            for (int c = 0; c < 2; ++c) {
                #pragma unroll
                for (int i = 0; i < 8; ++i) {
                    float v = c ? bw[i].y : bw[i].x;
                    unsigned short hh = f2bf(v);
                    bh[c][i] = (short)hh;
                    bl[c][i] = (short)f2bf(v - bf2f(hh));
                }
                char* bb = Bbuf + (bnp * 2 + c) * 144 + bkg * 16;
                *(bf16x8*)(bb)      = bh[c];
                *(bf16x8*)(bb + 64) = bl[c];
            }
        }
        __syncthreads();
        if (kt + 1 < KT) GLOADS(kt + 1);

        bf16x8 ah[4], al[4], bh[4], bl[4];
        #pragma unroll
        for (int rt = 0; rt < 4; ++rt) {
            const char* ab = Abuf + (wr * 64 + rt * 16 + lc16) * 144 + lq4 * 16;
            ah[rt] = *(const bf16x8*)(ab);
            al[rt] = *(const bf16x8*)(ab + 64);
        }
        #pragma unroll
        for (int ct = 0; ct < 4; ++ct) {
            const char* bb = Bbuf + (wc * 64 + ct * 16 + lc16) * 144 + lq4 * 16;
            bh[ct] = *(const bf16x8*)(bb);
            bl[ct] = *(const bf16x8*)(bb + 64);
        }
        #pragma unroll
        for (int rt = 0; rt < 4; ++rt)
            #pragma unroll
            for (int ct = 0; ct < 4; ++ct) {
                acc[rt][ct] = __builtin_amdgcn_mfma_f32_16x16x32_bf16(ah[rt], bh[ct], acc[rt][ct], 0, 0, 0);
                acc[rt][ct] = __builtin_amdgcn_mfma_f32_16x16x32_bf16(al[rt], bh[ct], acc[rt][ct], 0, 0, 0);
                acc[rt][ct] = __builtin_amdgcn_mfma_f32_16x16x32_bf16(ah[rt], bl[ct], acc[rt][ct], 0, 0, 0);
            }
    }
#undef GLOADS

    #pragma unroll
    for (int ct = 0; ct < 4; ++ct) {
        const int n = n0 + wc * 64 + ct * 16 + lc16;
        const float bn = bias[n];
        #pragma unroll
        for (int rt = 0; rt < 4; ++rt) {
            const int m = m0 + wr * 64 + rt * 16 + lq4 * 4;
            f32x4 v = acc[rt][ct];
            uint2 pk;
            pk.x = (unsigned)f2bf(v.x + bn) | ((unsigned)f2bf(v.y + bn) << 16);
            pk.y = (unsigned)f2bf(v.z + bn) | ((unsigned)f2bf(v.w + bn) << 16);
            *(uint2*)(XWt + (size_t)n * MTOT + m) = pk;
        }
    }
}

// ---------------------------------------------------------------------------
// MFMA recurrent scan — R10 structure (proven 2.29 ms), single change:
// only wave 0 polls the producer flags; a barrier right after releases the
// other waves (4x less uncached poll traffic at the MALL). xw loads stay
// BEFORE the poll so their HBM latency is absorbed by the spin (R12 lesson).
// 32 blocks x 256 thr (4 waves), dir = blk&1, P = blk>>1.
// ---------------------------------------------------------------------------
__global__ __launch_bounds__(256, 1) void lstm_scan11(
    const unsigned short* __restrict__ xw_f,   // [G4][MTOT] bf16
    const unsigned short* __restrict__ xw_b,
    const float* __restrict__ Wh_f,            // [512][2048] f32
    const float* __restrict__ Wh_b,
    float* __restrict__ out,                   // [B][T][1024] f32
    unsigned short* __restrict__ hbuf,         // [dir][par][P][b][32c] bf16 hi
    int* __restrict__ flags,                   // [dir][TSTEPS][16]
    int lval)                                  // layer+1
{
    extern __shared__ char smem[];
    float* ZL = (float*)(smem + HSZ);          // [128 zc][33]

    const int tid  = threadIdx.x;
    const int l    = tid & 63;
    const int w    = tid >> 6;
    const int dir  = blockIdx.x & 1;
    const int P    = blockIdx.x >> 1;
    const int p_eff = P * 4 + w;
    const int lc16 = l & 15;
    const int lq4  = l >> 4;

    const unsigned short* __restrict__ xw = dir ? xw_b : xw_f;
    const float* __restrict__ Wh = dir ? Wh_b : Wh_f;
    char* hb  = (char*)hbuf + (size_t)dir * 65536;   // 32KB per parity, hi only
    int*  flg = flags + dir * TSTEPS * 16;

    // ---- one-time: Wh fragments -> registers (hi/lo bf16) ----
    bf16x8 wfh[16][2], wfl[16][2];
    #pragma unroll
    for (int ki = 0; ki < 16; ++ki) {
        #pragma unroll
        for (int ct = 0; ct < 2; ++ct) {
            const int zc  = ct * 16 + lc16;
            const int col = p_eff * 8 + (zc & 7) + 512 * (zc >> 3);
            const float* src = Wh + (size_t)(ki * 32 + lq4 * 8) * G4 + col;
            bf16x8 vh, vl;
            #pragma unroll
            for (int r = 0; r < 8; ++r) {
                float v = src[(size_t)r * G4];
                unsigned short h16 = f2bf(v);
                vh[r] = (short)h16;
                vl[r] = (short)f2bf(v - bf2f(h16));
            }
            wfh[ki][ct] = vh;
            wfl[ki][ct] = vl;
        }
    }

    const int gc0 = p_eff * 8 + (lc16 & 7) + 512 * (lc16 >> 3);
    const unsigned short* xc0 = xw + (size_t)gc0 * MTOT;
    const unsigned short* xc1 = xw + (size_t)(gc0 + 1024) * MTOT;

    const int gb = tid & 31;                   // gate-thread batch
    const int jg = tid >> 5;                   // col group (cols jg*4..+3)
    float* outg = out + (size_t)gb * TSTEPS * OUTW + dir * HID + P * 32 + jg * 4;
    float cq[4] = {0.f, 0.f, 0.f, 0.f};

    for (int s = 0; s < TSTEPS; ++s) {
        const int t = dir ? (TSTEPS - 1 - s) : s;

        // xw loads BEFORE the poll: HBM latency absorbed by the spin (R12 lesson)
        const int xoff = t * 32 + lq4 * 4;
        uint2 u00 = *(const uint2*)(xc0 + xoff);
        uint2 u10 = *(const uint2*)(xc0 + xoff + 16);
        uint2 u01 = *(const uint2*)(xc1 + xoff);
        uint2 u11 = *(const uint2*)(xc1 + xoff + 16);

        f32x4 acc00 = {0,0,0,0}, acc01 = {0,0,0,0}, acc10 = {0,0,0,0}, acc11 = {0,0,0,0};

        if (s > 0) {
            // ---- only wave 0 polls; barrier releases waves 1-3 ----
            if (w == 0) {
                const int* fp = &flg[(s - 1) * 16 + (l & 15)];
                int fv;
                do {
                    asm volatile("global_load_dword %0, %1, off sc0 sc1\n\t"
                                 "s_waitcnt vmcnt(0)"
                                 : "=v"(fv) : "v"(fp) : "memory");
                } while (__any(fv != lval));
            }
            __syncthreads();   // [bar 1] flags seen + prev LDS reads complete

            // ---- issue 8 staging loads (32KB hi plane) ----
            const char* hsrc = hb + ((s - 1) & 1) * 32768;
            float4 rg[8];
            #pragma unroll
            for (int c = 0; c < 8; ++c) {
                const char* sp = hsrc + c * 4096 + tid * 16;
                asm volatile("global_load_dwordx4 %0, %1, off sc0 sc1"
                             : "=v"(rg[c]) : "v"(sp) : "memory");
            }
#define STG_WRITE(C0) do { \
            _Pragma("unroll") \
            for (int c = (C0); c < (C0) + 4; ++c) { \
                const int ip  = c * 4096 + tid * 16; \
                const int Pq  = ip >> 11; \
                const int b   = (ip >> 6) & 31; \
                const int jb  = ip & 63; \
                *(float4*)(smem + (Pq * 4 + (jb >> 4)) * KROW + b * 16) = rg[c]; \
            } } while (0)
            asm volatile("s_waitcnt vmcnt(4)" ::: "memory");
            __builtin_amdgcn_sched_barrier(0);
            STG_WRITE(0);
            asm volatile("s_waitcnt vmcnt(0)" ::: "memory");
            __builtin_amdgcn_sched_barrier(0);
            STG_WRITE(4);
#undef STG_WRITE
            __syncthreads();                               // [bar 2]

            // ---- MFMA: A (h hi) from LDS, B (Wh hi+lo) from registers ----
            #pragma unroll
            for (int ki = 0; ki < 16; ++ki) {
                const char* ra = smem + (ki * 4 + lq4) * KROW + lc16 * 16;
                bf16x8 ah0 = *(const bf16x8*)ra;
                bf16x8 ah1 = *(const bf16x8*)(ra + 256);
                acc00 = __builtin_amdgcn_mfma_f32_16x16x32_bf16(ah0, wfh[ki][0], acc00, 0, 0, 0);
                acc10 = __builtin_amdgcn_mfma_f32_16x16x32_bf16(ah1, wfh[ki][0], acc10, 0, 0, 0);
                acc01 = __builtin_amdgcn_mfma_f32_16x16x32_bf16(ah0, wfh[ki][1], acc01, 0, 0, 0);
                acc11 = __builtin_amdgcn_mfma_f32_16x16x32_bf16(ah1, wfh[ki][1], acc11, 0, 0, 0);
                acc00 = __builtin_amdgcn_mfma_f32_16x16x32_bf16(ah0, wfl[ki][0], acc00, 0, 0, 0);
                acc10 = __builtin_amdgcn_mfma_f32_16x16x32_bf16(ah1, wfl[ki][0], acc10, 0, 0, 0);
                acc01 = __builtin_amdgcn_mfma_f32_16x16x32_bf16(ah0, wfl[ki][1], acc01, 0, 0, 0);
                acc11 = __builtin_amdgcn_mfma_f32_16x16x32_bf16(ah1, wfl[ki][1], acc11, 0, 0, 0);
            }
        } else {
            __syncthreads();                               // keep barrier count uniform
        }

        // ---- add xw ----
        addxw(acc00, u00); addxw(acc10, u10);
        addxw(acc01, u01); addxw(acc11, u11);

        // ---- z -> ZL[zc][b], stride 33 ----
        {
            const int cb = w * 32 + lc16;
            const int r0 = lq4 * 4;
            #pragma unroll
            for (int i = 0; i < 4; ++i) {
                ZL[cb * 33 + r0 + i]             = acc00[i];
                ZL[cb * 33 + 16 + r0 + i]        = acc10[i];
                ZL[(cb + 16) * 33 + r0 + i]      = acc01[i];
                ZL[(cb + 16) * 33 + 16 + r0 + i] = acc11[i];
            }
        }
        __syncthreads();                                   // [bar 3]

        // ---- gates: thread (b=gb, cols jg*4..+3) ----
        float hv[4];
        #pragma unroll
        for (int q = 0; q < 4; ++q) {
            const int j  = jg * 4 + q;
            const int wv = j >> 3;
            const int jj = j & 7;
            const int zb = wv * 32;
            float zi = ZL[(zb + jj) * 33 + gb];
            float zf = ZL[(zb + 8 + jj) * 33 + gb];
            float zg = ZL[(zb + 16 + jj) * 33 + gb];
            float zo = ZL[(zb + 24 + jj) * 33 + gb];
            float ig = sigf(zi);
            float fg = sigf(zf);
            float gg = tanhf_fast(zg);
            float og = sigf(zo);
            cq[q] = fmaf(fg, cq[q], ig * gg);
            hv[q] = og * tanhf_fast(cq[q]);
        }

        // ---- publish bf16-hi to MALL ----
        {
            unsigned short h0 = f2bf(hv[0]), h1 = f2bf(hv[1]);
            unsigned short h2 = f2bf(hv[2]), h3 = f2bf(hv[3]);
            uint2 hi_pk;
            hi_pk.x = (unsigned)h0 | ((unsigned)h1 << 16);
            hi_pk.y = (unsigned)h2 | ((unsigned)h3 << 16);
            char* wp = hb + (s & 1) * 32768 + P * 2048 + gb * 64 + jg * 8;
            asm volatile("global_store_dwordx2 %0, %1, off sc0 sc1"
                         :: "v"(wp), "v"(hi_pk) : "memory");
        }
        asm volatile("s_waitcnt vmcnt(0)" ::: "memory");   // h stores at MALL
        __syncthreads();                                   // [bar 4] all drained
        if (tid == 0) {
            int* fp = &flg[s * 16 + P];
            asm volatile("global_store_dword %0, %1, off sc0 sc1"
                         :: "v"(fp), "v"(lval) : "memory");
        }
        // output store off the critical path
        float4 ov; ov.x = hv[0]; ov.y = hv[1]; ov.z = hv[2]; ov.w = hv[3];
        *(float4*)&outg[(size_t)t * OUTW] = ov;
    }
}

extern "C" void kernel_launch(void* const* d_in, const int* in_sizes, int n_in,
                              void* d_out, int out_size, void* d_ws, size_t ws_size,
                              hipStream_t stream)
{
    const float* x     = (const float*)d_in[0];
    const float* Wi_f0 = (const float*)d_in[1];
    const float* Wh_f0 = (const float*)d_in[2];
    const float* b_f0  = (const float*)d_in[3];
    const float* Wi_b0 = (const float*)d_in[4];
    const float* Wh_b0 = (const float*)d_in[5];
    const float* b_b0  = (const float*)d_in[6];
    const float* Wi_f1 = (const float*)d_in[7];
    const float* Wh_f1 = (const float*)d_in[8];
    const float* b_b1_unused = nullptr; (void)b_b1_unused;
    const float* b_f1  = (const float*)d_in[9];
    const float* Wi_b1 = (const float*)d_in[10];
    const float* Wh_b1 = (const float*)d_in[11];
    const float* b_b1  = (const float*)d_in[12];
    float* out = (float*)d_out;

    const size_t xw_elems = (size_t)MTOT * G4;                 // 33,554,432
    unsigned short* xwf = (unsigned short*)d_ws;
    unsigned short* xwb = xwf + xw_elems;
    char* tail = (char*)d_ws + 2 * xw_elems * sizeof(unsigned short);  // 128 MiB
    unsigned short* hbuf = (unsigned short*)tail;              // [dir][2 par][32KB]
    int* flags = (int*)(tail + 262144);                        // [dir][512][16]

    (void)hipMemsetAsync(flags, 0, 2 * TSTEPS * 16 * sizeof(int), stream);

    dim3 ggrid(G4 / 128, MTOT / 128);                          // (16, 128)
    dim3 gblock(256);
    const size_t gsmem = 36864;
    dim3 sgrid(2 * NBLK);                                      // 32 blocks
    dim3 sblock(256);
    const size_t ssmem = HSZ + ZLBYTES;                        // 50,688 B

    gemm_xw_mfma<<<ggrid, gblock, gsmem, stream>>>(x, 256, Wi_f0, b_f0, xwf);
    gemm_xw_mfma<<<ggrid, gblock, gsmem, stream>>>(x, 256, Wi_b0, b_b0, xwb);
    lstm_scan11<<<sgrid, sblock, ssmem, stream>>>(xwf, xwb, Wh_f0, Wh_b0, out,
                                                  hbuf, flags, 1);
    gemm_xw_mfma<<<ggrid, gblock, gsmem, stream>>>(out, 1024, Wi_f1, b_f1, xwf);
    gemm_xw_mfma<<<ggrid, gblock, gsmem, stream>>>(out, 1024, Wi_b1, b_b1, xwb);
    lstm_scan11<<<sgrid, sblock, ssmem, stream>>>(xwf, xwb, Wh_f1, Wh_b1, out,
                                                  hbuf, flags, 2);
}

// Round 15
// 4906.244 us; speedup vs baseline: 1.2979x; 1.0851x over previous
//
#include <hip/hip_runtime.h>
#include <stdint.h>

#define TSTEPS 512
#define BATCH  32
#define HID    512
#define G4     2048
#define OUTW   1024
#define MTOT   (TSTEPS * BATCH)   // 16384, m = t*32 + b

#define KROW   528                // HST row stride (bytes)
#define HSZ    (64 * KROW)        // 33792 B (single hi plane)
#define ZLBYTES (128 * 33 * 4)    // 16896 B

typedef __attribute__((ext_vector_type(8))) short bf16x8;
typedef __attribute__((ext_vector_type(4))) float f32x4;

struct ScanCtl { int xcd[8]; int g; int w; int dec; int pad[5]; };   // 64 B

__device__ __forceinline__ float sigf(float x) { return 1.0f / (1.0f + __expf(-x)); }
__device__ __forceinline__ float tanhf_fast(float x) { return 2.0f / (1.0f + __expf(-2.0f * x)) - 1.0f; }

__device__ __forceinline__ unsigned short f2bf(float f) {
    unsigned int u = __float_as_uint(f);
    u += 0x7fffu + ((u >> 16) & 1u);
    return (unsigned short)(u >> 16);
}
__device__ __forceinline__ float bf2f(unsigned short u) {
    return __uint_as_float((unsigned int)u << 16);
}
__device__ __forceinline__ void addxw(f32x4& a, uint2 u) {
    a.x += bf2f((unsigned short)(u.x & 0xffff));
    a.y += bf2f((unsigned short)(u.x >> 16));
    a.z += bf2f((unsigned short)(u.y & 0xffff));
    a.w += bf2f((unsigned short)(u.y >> 16));
}

// ---------------------------------------------------------------------------
// MFMA input-projection GEMM (proven R7), transposed bf16 XWt[n][m].
// ---------------------------------------------------------------------------
__global__ __launch_bounds__(256) void gemm_xw_mfma(
    const float* __restrict__ X, int K,
    const float* __restrict__ W,
    const float* __restrict__ bias,
    unsigned short* __restrict__ XWt)
{
    extern __shared__ char gsm[];
    char* Abuf = gsm;
    char* Bbuf = gsm + 18432;

    const int tid = threadIdx.x;
    const int n0 = blockIdx.x * 128;
    const int m0 = blockIdx.y * 128;
    const int w  = tid >> 6;
    const int l  = tid & 63;
    const int lc16 = l & 15;
    const int lq4  = l >> 4;
    const int wr = w >> 1, wc = w & 1;

    const int ar  = tid >> 1;
    const int akh = tid & 1;
    const int mg  = m0 + ar;
    const float* aptr = X + (size_t)(mg & 31) * ((size_t)TSTEPS * K)
                          + (size_t)(mg >> 5) * K + akh * 16;
    const int bnp = tid & 63;
    const int bkg = tid >> 6;
    const float* bptr = W + n0 + bnp * 2;

    f32x4 acc[4][4];
    #pragma unroll
    for (int i = 0; i < 4; ++i)
        #pragma unroll
        for (int j = 0; j < 4; ++j) acc[i][j] = (f32x4){0.f, 0.f, 0.f, 0.f};

    const int KT = K >> 5;
    float4 a0, a1, a2, a3;
    float2 bw[8];

#define GLOADS(KT0) do { \
    const float* ap = aptr + (KT0) * 32; \
    a0 = *(const float4*)(ap);      a1 = *(const float4*)(ap + 4); \
    a2 = *(const float4*)(ap + 8);  a3 = *(const float4*)(ap + 12); \
    _Pragma("unroll") \
    for (int i = 0; i < 8; ++i) \
        bw[i] = *(const float2*)(bptr + (size_t)((KT0) * 32 + bkg * 8 + i) * G4); \
} while (0)

    GLOADS(0);

    for (int kt = 0; kt < KT; ++kt) {
        __syncthreads();
        {
            float av[16] = {a0.x,a0.y,a0.z,a0.w, a1.x,a1.y,a1.z,a1.w,
                            a2.x,a2.y,a2.z,a2.w, a3.x,a3.y,a3.z,a3.w};
            bf16x8 h0, h1, l0, l1;
            #pragma unroll
            for (int i = 0; i < 8; ++i) {
                unsigned short hh = f2bf(av[i]);
                h0[i] = (short)hh; l0[i] = (short)f2bf(av[i] - bf2f(hh));
                unsigned short hh2 = f2bf(av[i + 8]);
                h1[i] = (short)hh2; l1[i] = (short)f2bf(av[i + 8] - bf2f(hh2));
            }
            char* ab = Abuf + ar * 144 + akh * 32;
            *(bf16x8*)(ab)      = h0;
            *(bf16x8*)(ab + 16) = h1;
            *(bf16x8*)(ab + 64) = l0;
            *(bf16x8*)(ab + 80) = l1;
        }
        {
            bf16x8 bh[2], bl[2];
            #pragma unroll
            for (int c = 0; c < 2; ++c) {
                #pragma unroll
                for (int i = 0; i < 8; ++i) {
                    float v = c ? bw[i].y : bw[i].x;
                    unsigned short hh = f2bf(v);
                    bh[c][i] = (short)hh;
                    bl[c][i] = (short)f2bf(v - bf2f(hh));
                }
                char* bb = Bbuf + (bnp * 2 + c) * 144 + bkg * 16;
                *(bf16x8*)(bb)      = bh[c];
                *(bf16x8*)(bb + 64) = bl[c];
            }
        }
        __syncthreads();
        if (kt + 1 < KT) GLOADS(kt + 1);

        bf16x8 ah[4], al[4], bh[4], bl[4];
        #pragma unroll
        for (int rt = 0; rt < 4; ++rt) {
            const char* ab = Abuf + (wr * 64 + rt * 16 + lc16) * 144 + lq4 * 16;
            ah[rt] = *(const bf16x8*)(ab);
            al[rt] = *(const bf16x8*)(ab + 64);
        }
        #pragma unroll
        for (int ct = 0; ct < 4; ++ct) {
            const char* bb = Bbuf + (wc * 64 + ct * 16 + lc16) * 144 + lq4 * 16;
            bh[ct] = *(const bf16x8*)(bb);
            bl[ct] = *(const bf16x8*)(bb + 64);
        }
        #pragma unroll
        for (int rt = 0; rt < 4; ++rt)
            #pragma unroll
            for (int ct = 0; ct < 4; ++ct) {
                acc[rt][ct] = __builtin_amdgcn_mfma_f32_16x16x32_bf16(ah[rt], bh[ct], acc[rt][ct], 0, 0, 0);
                acc[rt][ct] = __builtin_amdgcn_mfma_f32_16x16x32_bf16(al[rt], bh[ct], acc[rt][ct], 0, 0, 0);
                acc[rt][ct] = __builtin_amdgcn_mfma_f32_16x16x32_bf16(ah[rt], bl[ct], acc[rt][ct], 0, 0, 0);
            }
    }
#undef GLOADS

    #pragma unroll
    for (int ct = 0; ct < 4; ++ct) {
        const int n = n0 + wc * 64 + ct * 16 + lc16;
        const float bn = bias[n];
        #pragma unroll
        for (int rt = 0; rt < 4; ++rt) {
            const int m = m0 + wr * 64 + rt * 16 + lq4 * 4;
            f32x4 v = acc[rt][ct];
            uint2 pk;
            pk.x = (unsigned)f2bf(v.x + bn) | ((unsigned)f2bf(v.y + bn) << 16);
            pk.y = (unsigned)f2bf(v.z + bn) | ((unsigned)f2bf(v.w + bn) << 16);
            *(uint2*)(XWt + (size_t)n * MTOT + m) = pk;
        }
    }
}

// ---------------------------------------------------------------------------
// Scan body (R13-proven). Flags: ALWAYS the proven MALL (sc0 sc1) protocol.
// FAST only changes the bulk h exchange: publish = plain store (acks at the
// shared same-XCD L2), stage load = sc0 (L2 read). Ordering: h drained to L2
// before the MALL flag is stored; consumers share that L2.
// ---------------------------------------------------------------------------
template <bool FAST>
__device__ void run_scan(
    const unsigned short* __restrict__ xw,
    const float* __restrict__ Wh,
    float* __restrict__ out,
    char* hb, int* flg, int lval, int dir, int P)
{
    extern __shared__ char smem[];
    float* ZL = (float*)(smem + HSZ);

    const int tid  = threadIdx.x;
    const int l    = tid & 63;
    const int w    = tid >> 6;
    const int p_eff = P * 4 + w;
    const int lc16 = l & 15;
    const int lq4  = l >> 4;

    // ---- one-time: Wh fragments -> registers (hi/lo bf16) ----
    bf16x8 wfh[16][2], wfl[16][2];
    #pragma unroll
    for (int ki = 0; ki < 16; ++ki) {
        #pragma unroll
        for (int ct = 0; ct < 2; ++ct) {
            const int zc  = ct * 16 + lc16;
            const int col = p_eff * 8 + (zc & 7) + 512 * (zc >> 3);
            const float* src = Wh + (size_t)(ki * 32 + lq4 * 8) * G4 + col;
            bf16x8 vh, vl;
            #pragma unroll
            for (int r = 0; r < 8; ++r) {
                float v = src[(size_t)r * G4];
                unsigned short h16 = f2bf(v);
                vh[r] = (short)h16;
                vl[r] = (short)f2bf(v - bf2f(h16));
            }
            wfh[ki][ct] = vh;
            wfl[ki][ct] = vl;
        }
    }

    const int gc0 = p_eff * 8 + (lc16 & 7) + 512 * (lc16 >> 3);
    const unsigned short* xc0 = xw + (size_t)gc0 * MTOT;
    const unsigned short* xc1 = xw + (size_t)(gc0 + 1024) * MTOT;

    const int gb = tid & 31;
    const int jg = tid >> 5;
    float* outg = out + (size_t)gb * TSTEPS * OUTW + dir * HID + P * 32 + jg * 4;
    float cq[4] = {0.f, 0.f, 0.f, 0.f};

    for (int s = 0; s < TSTEPS; ++s) {
        const int t = dir ? (TSTEPS - 1 - s) : s;

        // xw loads BEFORE the poll: HBM latency absorbed by the spin
        const int xoff = t * 32 + lq4 * 4;
        uint2 u00 = *(const uint2*)(xc0 + xoff);
        uint2 u10 = *(const uint2*)(xc0 + xoff + 16);
        uint2 u01 = *(const uint2*)(xc1 + xoff);
        uint2 u11 = *(const uint2*)(xc1 + xoff + 16);

        f32x4 acc00 = {0,0,0,0}, acc01 = {0,0,0,0}, acc10 = {0,0,0,0}, acc11 = {0,0,0,0};

        if (s > 0) {
            // ---- proven MALL poll (wave 0 only; barrier releases others) ----
            if (w == 0) {
                const int* fp = &flg[(s - 1) * 16 + (l & 15)];
                int fv;
                do {
                    asm volatile("global_load_dword %0, %1, off sc0 sc1\n\t"
                                 "s_waitcnt vmcnt(0)"
                                 : "=v"(fv) : "v"(fp) : "memory");
                } while (__any(fv != lval));
            }
            __syncthreads();   // [bar 1]

            const char* hsrc = hb + ((s - 1) & 1) * 32768;
            float4 rg[8];
            #pragma unroll
            for (int c = 0; c < 8; ++c) {
                const char* sp = hsrc + c * 4096 + tid * 16;
                if constexpr (FAST)
                    asm volatile("global_load_dwordx4 %0, %1, off sc0"
                                 : "=v"(rg[c]) : "v"(sp) : "memory");
                else
                    asm volatile("global_load_dwordx4 %0, %1, off sc0 sc1"
                                 : "=v"(rg[c]) : "v"(sp) : "memory");
            }
#define STG_WRITE(C0) do { \
            _Pragma("unroll") \
            for (int c = (C0); c < (C0) + 4; ++c) { \
                const int ip  = c * 4096 + tid * 16; \
                const int Pq  = ip >> 11; \
                const int b   = (ip >> 6) & 31; \
                const int jb  = ip & 63; \
                *(float4*)(smem + (Pq * 4 + (jb >> 4)) * KROW + b * 16) = rg[c]; \
            } } while (0)
            asm volatile("s_waitcnt vmcnt(4)" ::: "memory");
            __builtin_amdgcn_sched_barrier(0);
            STG_WRITE(0);
            asm volatile("s_waitcnt vmcnt(0)" ::: "memory");
            __builtin_amdgcn_sched_barrier(0);
            STG_WRITE(4);
#undef STG_WRITE
            __syncthreads();                               // [bar 2]

            #pragma unroll
            for (int ki = 0; ki < 16; ++ki) {
                const char* ra = smem + (ki * 4 + lq4) * KROW + lc16 * 16;
                bf16x8 ah0 = *(const bf16x8*)ra;
                bf16x8 ah1 = *(const bf16x8*)(ra + 256);
                acc00 = __builtin_amdgcn_mfma_f32_16x16x32_bf16(ah0, wfh[ki][0], acc00, 0, 0, 0);
                acc10 = __builtin_amdgcn_mfma_f32_16x16x32_bf16(ah1, wfh[ki][0], acc10, 0, 0, 0);
                acc01 = __builtin_amdgcn_mfma_f32_16x16x32_bf16(ah0, wfh[ki][1], acc01, 0, 0, 0);
                acc11 = __builtin_amdgcn_mfma_f32_16x16x32_bf16(ah1, wfh[ki][1], acc11, 0, 0, 0);
                acc00 = __builtin_amdgcn_mfma_f32_16x16x32_bf16(ah0, wfl[ki][0], acc00, 0, 0, 0);
                acc10 = __builtin_amdgcn_mfma_f32_16x16x32_bf16(ah1, wfl[ki][0], acc10, 0, 0, 0);
                acc01 = __builtin_amdgcn_mfma_f32_16x16x32_bf16(ah0, wfl[ki][1], acc01, 0, 0, 0);
                acc11 = __builtin_amdgcn_mfma_f32_16x16x32_bf16(ah1, wfl[ki][1], acc11, 0, 0, 0);
            }
        } else {
            __syncthreads();
        }

        addxw(acc00, u00); addxw(acc10, u10);
        addxw(acc01, u01); addxw(acc11, u11);

        {
            const int cb = w * 32 + lc16;
            const int r0 = lq4 * 4;
            #pragma unroll
            for (int i = 0; i < 4; ++i) {
                ZL[cb * 33 + r0 + i]             = acc00[i];
                ZL[cb * 33 + 16 + r0 + i]        = acc10[i];
                ZL[(cb + 16) * 33 + r0 + i]      = acc01[i];
                ZL[(cb + 16) * 33 + 16 + r0 + i] = acc11[i];
            }
        }
        __syncthreads();                                   // [bar 3]

        float hv[4];
        #pragma unroll
        for (int q = 0; q < 4; ++q) {
            const int j  = jg * 4 + q;
            const int wv = j >> 3;
            const int jj = j & 7;
            const int zb = wv * 32;
            float zi = ZL[(zb + jj) * 33 + gb];
            float zf = ZL[(zb + 8 + jj) * 33 + gb];
            float zg = ZL[(zb + 16 + jj) * 33 + gb];
            float zo = ZL[(zb + 24 + jj) * 33 + gb];
            float ig = sigf(zi);
            float fg = sigf(zf);
            float gg = tanhf_fast(zg);
            float og = sigf(zo);
            cq[q] = fmaf(fg, cq[q], ig * gg);
            hv[q] = og * tanhf_fast(cq[q]);
        }

        {
            unsigned short h0 = f2bf(hv[0]), h1 = f2bf(hv[1]);
            unsigned short h2 = f2bf(hv[2]), h3 = f2bf(hv[3]);
            uint2 hi_pk;
            hi_pk.x = (unsigned)h0 | ((unsigned)h1 << 16);
            hi_pk.y = (unsigned)h2 | ((unsigned)h3 << 16);
            char* wp = hb + (s & 1) * 32768 + P * 2048 + gb * 64 + jg * 8;
            if constexpr (FAST)
                asm volatile("global_store_dwordx2 %0, %1, off"
                             :: "v"(wp), "v"(hi_pk) : "memory");
            else
                asm volatile("global_store_dwordx2 %0, %1, off sc0 sc1"
                             :: "v"(wp), "v"(hi_pk) : "memory");
        }
        asm volatile("s_waitcnt vmcnt(0)" ::: "memory");   // h acked (L2 or MALL)
        __syncthreads();                                   // [bar 4]
        if (tid == 0) {
            int* fp = &flg[s * 16 + P];
            asm volatile("global_store_dword %0, %1, off sc0 sc1"
                         :: "v"(fp), "v"(lval) : "memory");
        }
        float4 ov; ov.x = hv[0]; ov.y = hv[1]; ov.z = hv[2]; ov.w = hv[3];
        *(float4*)&outg[(size_t)t * OUTW] = ov;
    }
}

// ---------------------------------------------------------------------------
// Wrapper: race-free XCD election. Each block: count-add, vmcnt(0), presence-
// add. The block whose presence-add returns 255 runs only after ALL count-adds
// are MALL-visible -> it alone decides (fast, t0, t1) and publishes one word.
// Everyone spins on the decision -> globally consistent by construction.
// Fallback (any XCD < 16 blocks): proven R13 MALL protocol, raced worker ids.
// ---------------------------------------------------------------------------
__global__ __launch_bounds__(256, 1) void lstm_scan13(
    const unsigned short* __restrict__ xw_f,
    const unsigned short* __restrict__ xw_b,
    const float* __restrict__ Wh_f,
    const float* __restrict__ Wh_b,
    float* __restrict__ out,
    unsigned short* __restrict__ hbuf,
    int* __restrict__ flags,
    ScanCtl* __restrict__ ctl,
    int lval)
{
    extern __shared__ char smem[];
    int* sh = (int*)smem;
    const int tid = threadIdx.x;

    if (tid == 0) {
        int xcc = 0;
        asm volatile("s_getreg_b32 %0, hwreg(HW_REG_XCC_ID)" : "=s"(xcc));
        xcc &= 7;
        int rank = atomicAdd(&ctl->xcd[xcc], 1);
        asm volatile("s_waitcnt vmcnt(0)" ::: "memory");   // count-add visible FIRST
        int gold = atomicAdd(&ctl->g, 1);
        asm volatile("s_waitcnt vmcnt(0)" ::: "memory");
        if (gold == 255) {
            // all 256 presence-adds done => all count-adds are MALL-visible
            int c[8];
            #pragma unroll
            for (int i = 0; i < 8; ++i)
                asm volatile("global_load_dword %0, %1, off sc0 sc1\n\t"
                             "s_waitcnt vmcnt(0)"
                             : "=v"(c[i]) : "v"(&ctl->xcd[i]) : "memory");
            int t0 = 0;
            for (int i = 1; i < 8; ++i) if (c[i] > c[t0]) t0 = i;
            int t1 = (t0 == 0) ? 1 : 0;
            for (int i = 0; i < 8; ++i) if (i != t0 && c[i] > c[t1]) t1 = i;
            int fast = (c[t0] >= 16 && c[t1] >= 16) ? 1 : 0;
            int dec = 0x100 | fast | (t0 << 1) | (t1 << 4);
            asm volatile("global_store_dword %0, %1, off sc0 sc1"
                         :: "v"(&ctl->dec), "v"(dec) : "memory");
        }
        int dec;
        do {
            asm volatile("global_load_dword %0, %1, off sc0 sc1\n\t"
                         "s_waitcnt vmcnt(0)"
                         : "=v"(dec) : "v"(&ctl->dec) : "memory");
        } while (dec == 0);
        const int fast = dec & 1;
        const int t0 = (dec >> 1) & 7;
        const int t1 = (dec >> 4) & 7;
        int dir = -1, P = -1;
        if (fast) {
            if (xcc == t0 && rank < 16)      { dir = 0; P = rank; }
            else if (xcc == t1 && rank < 16) { dir = 1; P = rank; }
        } else {
            int wr = atomicAdd(&ctl->w, 1);
            if (wr < 32) { dir = wr & 1; P = wr >> 1; }
        }
        sh[0] = fast; sh[1] = dir; sh[2] = P;
    }
    __syncthreads();
    const int fast = sh[0];
    const int dir  = sh[1];
    const int P    = sh[2];
    __syncthreads();          // everyone has read sh[] before smem reuse
    if (P < 0) return;

    const unsigned short* xw = dir ? xw_b : xw_f;
    const float* Wh = dir ? Wh_b : Wh_f;
    char* hb  = (char*)hbuf + (size_t)dir * 65536;
    int*  flg = flags + dir * TSTEPS * 16;

    if (fast) run_scan<true >(xw, Wh, out, hb, flg, lval, dir, P);
    else      run_scan<false>(xw, Wh, out, hb, flg, lval, dir, P);
}

extern "C" void kernel_launch(void* const* d_in, const int* in_sizes, int n_in,
                              void* d_out, int out_size, void* d_ws, size_t ws_size,
                              hipStream_t stream)
{
    const float* x     = (const float*)d_in[0];
    const float* Wi_f0 = (const float*)d_in[1];
    const float* Wh_f0 = (const float*)d_in[2];
    const float* b_f0  = (const float*)d_in[3];
    const float* Wi_b0 = (const float*)d_in[4];
    const float* Wh_b0 = (const float*)d_in[5];
    const float* b_b0  = (const float*)d_in[6];
    const float* Wi_f1 = (const float*)d_in[7];
    const float* Wh_f1 = (const float*)d_in[8];
    const float* b_f1  = (const float*)d_in[9];
    const float* Wi_b1 = (const float*)d_in[10];
    const float* Wh_b1 = (const float*)d_in[11];
    const float* b_b1  = (const float*)d_in[12];
    float* out = (float*)d_out;

    const size_t xw_elems = (size_t)MTOT * G4;                 // 33,554,432
    unsigned short* xwf = (unsigned short*)d_ws;
    unsigned short* xwb = xwf + xw_elems;
    char* tail = (char*)d_ws + 2 * xw_elems * sizeof(unsigned short);  // 128 MiB
    unsigned short* hbuf = (unsigned short*)tail;              // [dir][2 par][32KB]
    int* flags = (int*)(tail + 262144);                        // [dir][512][16] = 64KB
    ScanCtl* ctl = (ScanCtl*)(tail + 262144 + 65536);          // 2 x 64B

    (void)hipMemsetAsync(flags, 0,
                         2 * TSTEPS * 16 * sizeof(int) + 2 * sizeof(ScanCtl),
                         stream);

    dim3 ggrid(G4 / 128, MTOT / 128);                          // (16, 128)
    dim3 gblock(256);
    const size_t gsmem = 36864;
    dim3 sgrid(256);                                           // all CUs; workers elected
    dim3 sblock(256);
    const size_t ssmem = HSZ + ZLBYTES;                        // 50,688 B

    gemm_xw_mfma<<<ggrid, gblock, gsmem, stream>>>(x, 256, Wi_f0, b_f0, xwf);
    gemm_xw_mfma<<<ggrid, gblock, gsmem, stream>>>(x, 256, Wi_b0, b_b0, xwb);
    lstm_scan13<<<sgrid, sblock, ssmem, stream>>>(xwf, xwb, Wh_f0, Wh_b0, out,
                                                  hbuf, flags, ctl + 0, 1);
    gemm_xw_mfma<<<ggrid, gblock, gsmem, stream>>>(out, 1024, Wi_f1, b_f1, xwf);
    gemm_xw_mfma<<<ggrid, gblock, gsmem, stream>>>(out, 1024, Wi_b1, b_b1, xwb);
    lstm_scan13<<<sgrid, sblock, ssmem, stream>>>(xwf, xwb, Wh_f1, Wh_b1, out,
                                                  hbuf, flags, ctl + 1, 2);
}